// Round 12
// baseline (776.470 us; speedup 1.0000x reference)
//
#include <hip/hip_runtime.h>
#include <hip/hip_cooperative_groups.h>

namespace cg = cooperative_groups;

// Problem constants (hardcoded in the reference)
#define NPIX 65536   // 256*256 = 2^16
#define KK   361     // 19*19
#define LSZ  19
#define HWD  256
#define QB   16      // q-rows per sub-tile (phase C)
#define CT   4       // sub-tiles per chunk
#define CHUNK 64     // q per block
#define GPART 1024   // blocks
#define NTHR 384
#define NSLOT 8      // partial slots per row (window <= 7, one 64B line)
#define NS2  16      // s-strips for S1
#define SPS2 23      // s-rows per strip (last: 361 - 15*23 = 16)
#define DTC  82      // in2 LDS tile cols = CHUNK-1 + LSZ

// reflect-pad index (pad=9, size 256, mode="reflect"); arg is (coord + offset)
__device__ __forceinline__ int refl(int v) {
    v -= 9;
    v = v < 0 ? -v : v;
    v = v > 255 ? 510 - v : v;
    return v;
}

// ---------------------------------------------------------------------------
// Cooperative mega-kernel: S1a | sync | S1b | sync | k_part(R9) | sync | out.
// Fusion removes 3 launch gaps and makes the hot code visible to rocprof.
// ---------------------------------------------------------------------------
__global__ __launch_bounds__(NTHR, 6) void k_mega(const float* __restrict__ ker,
                                                  const float* __restrict__ in2,
                                                  float* __restrict__ out,
                                                  float* __restrict__ ws) {
    float*  rcpS1   = ws;                                   // NPIX
    float*  s1part  = ws + NPIX;                            // NS2*NPIX
    float2* partial = (float2*)(ws + NPIX + NS2 * NPIX);    // NPIX*NSLOT float2

    __shared__ float tile[QB * KK];      // 23,104 B
    __shared__ float dt[LSZ * DTC];      // 6,232 B
    __shared__ float rcpS2s[QB];

    cg::grid_group gg = cg::this_grid();
    const int tid = threadIdx.x;
    const int blk = blockIdx.x;
    const int gid = blk * NTHR + tid;

    // ---- Phase A: S1a partial column sums (the only cold HBM read) ----
    if (gid < NS2 * (NPIX / 4)) {
        const int strip = gid >> 14;                 // / 16384
        const int p4    = gid & ((NPIX / 4) - 1);
        const int s0 = strip * SPS2;
        const int n  = (strip == NS2 - 1) ? (KK - s0) : SPS2;
        const float4* kp = (const float4*)ker + (size_t)s0 * (NPIX / 4) + p4;
        float4 acc = {0.f, 0.f, 0.f, 0.f};
#pragma unroll 8
        for (int s = 0; s < n; ++s) {
            float4 v = kp[(size_t)s * (NPIX / 4)];
            acc.x += v.x; acc.y += v.y; acc.z += v.z; acc.w += v.w;
        }
        ((float4*)s1part)[(size_t)strip * (NPIX / 4) + p4] = acc;
    }
    __threadfence();
    gg.sync();

    // ---- Phase B: S1b reduce strips -> rcpS1 ----
    if (gid < NPIX / 4) {
        float4 a = {0.f, 0.f, 0.f, 0.f};
#pragma unroll
        for (int s = 0; s < NS2; ++s) {
            float4 v = ((const float4*)s1part)[(size_t)s * (NPIX / 4) + gid];
            a.x += v.x; a.y += v.y; a.z += v.z; a.w += v.w;
        }
        ((float4*)rcpS1)[gid] = float4{1.0f / a.x, 1.0f / a.y, 1.0f / a.z, 1.0f / a.w};
    }
    __threadfence();
    gg.sync();

    // ---- Phase C: k_part (R9 structure, verbatim) ----
    {
        const int lb = ((blk & 7) << 7) | (blk >> 3);   // XCD swizzle, 1024 = 8*128
        const int q0 = lb * CHUNK;

        // stage reflected in2 patch (consumed after the k=0 stage barrier)
        {
            const int y0 = q0 >> 8, x0 = q0 & 255;
            for (int i = tid; i < LSZ * DTC; i += NTHR) {
                int ai = i / DTC, ci = i - ai * DTC;
                dt[i] = in2[refl(y0 + ai) * HWD + refl(x0 + ci)];
            }
        }

        // per-lane chunk-carry state
        const int t  = tid;
        const int j0 = t * NPIX + q0;             // < 2^25
        const int r0 = j0 / KK;
        const int jm = j0 - r0 * KK;
        const int d0 = (jm == 0) ? CHUNK : (KK - jm);
        const int split = d0 < CHUNK ? d0 : CHUNK;     // [1, 64]
        const int la = t / LSZ, lb2 = t - LSZ * la;
        const int dbase = la * DTC + lb2;
        float ad = 0.f, as = 0.f, sd = 0.f, ss = 0.f;
        const int wave = tid >> 6, lane = tid & 63;

        for (int k = 0; k < CT; ++k) {
            __syncthreads();   // previous sub-tile fully consumed (and dt, k=0)
            // stage ker sub-tile k (coalesced float4), scaled by rcpS1
            const int basek = (q0 + k * QB) * KK;            // %4 == 0
            const float4* k4 = (const float4*)(ker + basek);
            for (int i = tid; i < (QB * KK) / 4; i += NTHR) {
                float4 v = k4[i];
                int m = basek + i * 4;
                const float4 s = *(const float4*)(rcpS1 + (m & (NPIX - 1)));
                v.x *= s.x; v.y *= s.y; v.z *= s.z; v.w *= s.w;
                *(float4*)(tile + i * 4) = v;
            }
            __syncthreads();
            // per-q row sums -> rcpS2s
            for (int qq = wave; qq < QB; qq += 6) {
                float acc = 0.f;
                for (int e = lane; e < KK; e += 64) acc += tile[qq * KK + e];
                for (int m = 1; m < 64; m <<= 1) acc += __shfl_xor(acc, m);
                if (lane == 0) rcpS2s[qq] = 1.0f / acc;
            }
            __syncthreads();
            if (t < KK) {
#pragma unroll
                for (int o = 0; o < QB; ++o) {
                    const int off = k * QB + o;
                    if (off == split) { sd = ad; ss = as; }  // snapshot at boundary
                    float v = tile[o * KK + t] * rcpS2s[o];
                    float d = dt[dbase + off];
                    ad += d * v;
                    as += v;
                }
            }
        }

        if (t < KK) {
            const int slot = lb & (NSLOT - 1);
            if (split == CHUNK) {
                partial[(size_t)r0 * NSLOT + slot] = float2{ad, as};
            } else {
                partial[(size_t)r0 * NSLOT + slot] = float2{sd, ss};
                partial[(size_t)(r0 + 1) * NSLOT + slot] = float2{ad - sd, as - ss};
            }
        }
    }
    __threadfence();
    gg.sync();

    // ---- Phase D: final slot-window reduction -> out ----
    if (gid < NPIX) {
        const int r = gid;
        const int j0d = r * KK;
        const int qs = j0d & (NPIX - 1);
        const int ql = (j0d + KK - 1) & (NPIX - 1);
        const int first = qs >> 6;
        const int last  = ql >> 6;
        const int cnt = ((last - first) & (GPART - 1)) + 1;
        const float2* p = partial + (size_t)r * NSLOT;
        float dot = 0.f, sum = 0.f;
        for (int i = 0; i < cnt; ++i) {
            float2 v = p[(first + i) & (NSLOT - 1)];
            dot += v.x; sum += v.y;
        }
        out[r] = dot / sum;
    }
}

// ---------------------------------------------------------------------------
// Fallback path: R9's proven 4-kernel pipeline (51.4 us), used if the
// cooperative launch is rejected (capture-incompatible or residency fail).
// ---------------------------------------------------------------------------
__global__ __launch_bounds__(256) void k_s1a(const float4* __restrict__ ker4,
                                             float4* __restrict__ part4) {
    const int p4 = blockIdx.x * 256 + threadIdx.x;
    const int strip = blockIdx.y;
    const int s0 = strip * SPS2;
    const int n = (strip == NS2 - 1) ? (KK - s0) : SPS2;
    const float4* kp = ker4 + (size_t)s0 * (NPIX / 4) + p4;
    float4 acc = {0.f, 0.f, 0.f, 0.f};
#pragma unroll 8
    for (int s = 0; s < n; ++s) {
        float4 v = kp[(size_t)s * (NPIX / 4)];
        acc.x += v.x; acc.y += v.y; acc.z += v.z; acc.w += v.w;
    }
    part4[(size_t)strip * (NPIX / 4) + p4] = acc;
}

__global__ __launch_bounds__(256) void k_s1b(const float4* __restrict__ part4,
                                             float4* __restrict__ rcp4) {
    const int i = blockIdx.x * 256 + threadIdx.x;
    float4 a = {0.f, 0.f, 0.f, 0.f};
#pragma unroll
    for (int s = 0; s < NS2; ++s) {
        float4 v = part4[(size_t)s * (NPIX / 4) + i];
        a.x += v.x; a.y += v.y; a.z += v.z; a.w += v.w;
    }
    rcp4[i] = float4{1.0f / a.x, 1.0f / a.y, 1.0f / a.z, 1.0f / a.w};
}

__global__ __launch_bounds__(NTHR) void k_part(const float* __restrict__ ker,
                                               const float* __restrict__ rcpS1,
                                               const float* __restrict__ in2,
                                               float2* __restrict__ partial) {
    __shared__ float tile[QB * KK];
    __shared__ float dt[LSZ * DTC];
    __shared__ float rcpS2s[QB];
    const int tid = threadIdx.x;
    const int lb  = ((blockIdx.x & 7) << 7) | (blockIdx.x >> 3);
    const int q0  = lb * CHUNK;

    {
        const int y0 = q0 >> 8, x0 = q0 & 255;
        for (int i = tid; i < LSZ * DTC; i += NTHR) {
            int ai = i / DTC, ci = i - ai * DTC;
            dt[i] = in2[refl(y0 + ai) * HWD + refl(x0 + ci)];
        }
    }
    const int t  = tid;
    const int j0 = t * NPIX + q0;
    const int r0 = j0 / KK;
    const int jm = j0 - r0 * KK;
    const int d0 = (jm == 0) ? CHUNK : (KK - jm);
    const int split = d0 < CHUNK ? d0 : CHUNK;
    const int la = t / LSZ, lb2 = t - LSZ * la;
    const int dbase = la * DTC + lb2;
    float ad = 0.f, as = 0.f, sd = 0.f, ss = 0.f;
    const int wave = tid >> 6, lane = tid & 63;

    for (int k = 0; k < CT; ++k) {
        __syncthreads();
        const int basek = (q0 + k * QB) * KK;
        const float4* k4 = (const float4*)(ker + basek);
        for (int i = tid; i < (QB * KK) / 4; i += NTHR) {
            float4 v = k4[i];
            int m = basek + i * 4;
            const float4 s = *(const float4*)(rcpS1 + (m & (NPIX - 1)));
            v.x *= s.x; v.y *= s.y; v.z *= s.z; v.w *= s.w;
            *(float4*)(tile + i * 4) = v;
        }
        __syncthreads();
        for (int qq = wave; qq < QB; qq += 6) {
            float acc = 0.f;
            for (int e = lane; e < KK; e += 64) acc += tile[qq * KK + e];
            for (int m = 1; m < 64; m <<= 1) acc += __shfl_xor(acc, m);
            if (lane == 0) rcpS2s[qq] = 1.0f / acc;
        }
        __syncthreads();
        if (t < KK) {
#pragma unroll
            for (int o = 0; o < QB; ++o) {
                const int off = k * QB + o;
                if (off == split) { sd = ad; ss = as; }
                float v = tile[o * KK + t] * rcpS2s[o];
                float d = dt[dbase + off];
                ad += d * v;
                as += v;
            }
        }
    }

    if (t < KK) {
        const int slot = lb & (NSLOT - 1);
        if (split == CHUNK) {
            partial[(size_t)r0 * NSLOT + slot] = float2{ad, as};
        } else {
            partial[(size_t)r0 * NSLOT + slot] = float2{sd, ss};
            partial[(size_t)(r0 + 1) * NSLOT + slot] = float2{ad - sd, as - ss};
        }
    }
}

__global__ __launch_bounds__(256) void k_out2(const float2* __restrict__ partial,
                                              float* __restrict__ out) {
    const int r = blockIdx.x * 256 + threadIdx.x;
    const int j0 = r * KK;
    const int qs = j0 & (NPIX - 1);
    const int ql = (j0 + KK - 1) & (NPIX - 1);
    const int first = qs >> 6;
    const int last  = ql >> 6;
    const int cnt = ((last - first) & (GPART - 1)) + 1;
    const float2* p = partial + (size_t)r * NSLOT;
    float dot = 0.f, sum = 0.f;
    for (int i = 0; i < cnt; ++i) {
        float2 v = p[(first + i) & (NSLOT - 1)];
        dot += v.x; sum += v.y;
    }
    out[r] = dot / sum;
}

// Minimal-ws fallback: direct strided gathers.
__global__ __launch_bounds__(256) void k_s1(const float* __restrict__ ker,
                                            float* __restrict__ rcpS1) {
    int p = blockIdx.x * blockDim.x + threadIdx.x;
    const float* kp = ker + p;
    float a = 0.f;
    for (int s = 0; s < KK; ++s) a += kp[(size_t)s * NPIX];
    rcpS1[p] = 1.0f / a;
}

__global__ __launch_bounds__(256) void k_s2_fallback(const float* __restrict__ ker,
                                                     const float* __restrict__ rcpS1,
                                                     float* __restrict__ rcpS2) {
    int lane = threadIdx.x & 63;
    int q = blockIdx.x * 4 + (threadIdx.x >> 6);
    int base = q * KK;
    float acc = 0.f;
    for (int t = lane; t < KK; t += 64)
        acc += ker[base + t] * rcpS1[(base + t) & (NPIX - 1)];
    for (int m = 1; m < 64; m <<= 1) acc += __shfl_xor(acc, m);
    if (lane == 0) rcpS2[q] = 1.0f / acc;
}

__global__ __launch_bounds__(256) void k_out_fallback(const float* __restrict__ ker,
                                                      const float* __restrict__ rcpS1,
                                                      const float* __restrict__ rcpS2,
                                                      const float* __restrict__ in2,
                                                      float* __restrict__ out) {
    int lane = threadIdx.x & 63;
    int r = blockIdx.x * 4 + (threadIdx.x >> 6);
    float vsum = 0.f, vdot = 0.f;
    for (int u = lane; u < KK; u += 64) {
        int jj = r * KK + u;
        int t  = jj >> 16;
        int q  = jj & (NPIX - 1);
        int m  = q * KK + t;
        float v = ker[m] * rcpS1[m & (NPIX - 1)] * rcpS2[q];
        int y = q >> 8, x = q & 255;
        int a = t / LSZ, b = t - a * LSZ;
        float d = in2[refl(y + a) * HWD + refl(x + b)];
        vsum += v;
        vdot += d * v;
    }
    for (int mm = 1; mm < 64; mm <<= 1) {
        vsum += __shfl_xor(vsum, mm);
        vdot += __shfl_xor(vdot, mm);
    }
    if (lane == 0) out[r] = vdot / vsum;
}

extern "C" void kernel_launch(void* const* d_in, const int* in_sizes, int n_in,
                              void* d_out, int out_size, void* d_ws, size_t ws_size,
                              hipStream_t stream) {
    const float* inp = (const float*)d_in[0];   // (1,3,256,256)
    const float* ker = (const float*)d_in[1];   // (19,19,256,256)
    float* out = (float*)d_out;                 // (1,1,256,256)
    const float* in2 = inp + 2 * NPIX;          // channel 2
    float* wsf = (float*)d_ws;

    const size_t needed = ((size_t)NPIX * (1 + NS2) +
                           (size_t)NPIX * NSLOT * 2) * sizeof(float);  // ~8.25 MB

    if (ws_size >= needed) {
        void* args[] = {(void*)&ker, (void*)&in2, (void*)&out, (void*)&wsf};
        hipError_t e = hipLaunchCooperativeKernel(
            reinterpret_cast<const void*>(&k_mega),
            dim3(GPART), dim3(NTHR), args, 0u, stream);
        if (e != hipSuccess) {
            // R9 4-kernel fallback
            float*  rcpS1   = wsf;
            float*  s1part  = rcpS1 + NPIX;
            float2* partial = (float2*)(s1part + (size_t)NS2 * NPIX);
            dim3 g1(NPIX / 4 / 256, NS2);
            k_s1a<<<g1, 256, 0, stream>>>((const float4*)ker, (float4*)s1part);
            k_s1b<<<NPIX / 4 / 256, 256, 0, stream>>>((const float4*)s1part, (float4*)rcpS1);
            k_part<<<GPART, NTHR, 0, stream>>>(ker, rcpS1, in2, partial);
            k_out2<<<NPIX / 256, 256, 0, stream>>>(partial, out);
        }
    } else {
        float* rcpS1 = wsf;
        float* rcpS2 = rcpS1 + NPIX;   // fallback needs only 512 KB
        k_s1<<<NPIX / 256, 256, 0, stream>>>(ker, rcpS1);
        k_s2_fallback<<<NPIX / 4, 256, 0, stream>>>(ker, rcpS1, rcpS2);
        k_out_fallback<<<NPIX / 4, 256, 0, stream>>>(ker, rcpS1, rcpS2, in2, out);
    }
}

// Round 13
// 57.661 us; speedup vs baseline: 13.4662x; 13.4662x over previous
//
#include <hip/hip_runtime.h>

// Problem constants (hardcoded in the reference)
#define NPIX 65536   // 256*256 = 2^16
#define KK   361     // 19*19
#define LSZ  19
#define HWD  256
#define QB   16      // q-rows per sub-tile
#define CT   4       // sub-tiles per chunk
#define CHUNK 64     // q per block
#define GPART (NPIX / CHUNK)      // 1024 blocks
#define NTHR 384
#define NSLOT 8      // partial slots per row (window <= 7, one 64B line)
#define NS2  16      // s-strips for S1
#define SPS2 23      // s-rows per strip (last: 361 - 15*23 = 16)
#define DTC  82      // in2 LDS tile cols = CHUNK-1 + LSZ

// reflect-pad index (pad=9, size 256, mode="reflect"); arg is (coord + offset)
__device__ __forceinline__ int refl(int v) {
    v -= 9;
    v = v < 0 ? -v : v;
    v = v > 255 ? 510 - v : v;
    return v;
}

// ---------------------------------------------------------------------------
// S1a: partial column sums, contiguous float4 reads (the only cold HBM pass).
// ---------------------------------------------------------------------------
__global__ __launch_bounds__(256) void k_s1a(const float4* __restrict__ ker4,
                                             float4* __restrict__ part4) {
    const int p4 = blockIdx.x * 256 + threadIdx.x;   // [0, 16384)
    const int strip = blockIdx.y;
    const int s0 = strip * SPS2;
    const int n = (strip == NS2 - 1) ? (KK - s0) : SPS2;
    const float4* kp = ker4 + (size_t)s0 * (NPIX / 4) + p4;
    float4 acc = {0.f, 0.f, 0.f, 0.f};
#pragma unroll 8
    for (int s = 0; s < n; ++s) {
        float4 v = kp[(size_t)s * (NPIX / 4)];
        acc.x += v.x; acc.y += v.y; acc.z += v.z; acc.w += v.w;
    }
    part4[(size_t)strip * (NPIX / 4) + p4] = acc;
}

// S1b: rcpS1[p] = 1 / sum_strips
__global__ __launch_bounds__(256) void k_s1b(const float4* __restrict__ part4,
                                             float4* __restrict__ rcp4) {
    const int i = blockIdx.x * 256 + threadIdx.x;    // [0, 16384)
    float4 a = {0.f, 0.f, 0.f, 0.f};
#pragma unroll
    for (int s = 0; s < NS2; ++s) {
        float4 v = part4[(size_t)s * (NPIX / 4) + i];
        a.x += v.x; a.y += v.y; a.z += v.z; a.w += v.w;
    }
    rcp4[i] = float4{1.0f / a.x, 1.0f / a.y, 1.0f / a.z, 1.0f / a.w};
}

// ---------------------------------------------------------------------------
// k_part (R9 skeleton, slimmed):
//   phase 0: dt patch -> LDS; ALL 64 row-sums from global (L3-hot ker),
//            bit-identical order to R9's LDS rowsum -> rowrcp[64]. 1 sync.
//   per sub-tile k (4x): stage ker*rcpS1*rowrcp -> tile (premultiplied);
//            sync; accum (2 LDS reads + 2 FMA per elem); sync.
// 8 syncs total (R9: 12); accum drops the rcpS2 broadcast read; the
// per-subtile rowsum LDS phase is gone. Chunk-carry + snapshot unchanged.
// XCD swizzle keeps co-writers of each partial 64B line on one XCD.
// ---------------------------------------------------------------------------
__global__ __launch_bounds__(NTHR) void k_part(const float* __restrict__ ker,
                                               const float* __restrict__ rcpS1,
                                               const float* __restrict__ in2,
                                               float2* __restrict__ partial) {
    __shared__ float tile[QB * KK];      // 23,104 B
    __shared__ float dt[LSZ * DTC];      // 6,232 B
    __shared__ float rowrcp[CHUNK];      // 256 B
    const int tid = threadIdx.x;
    const int lb  = ((blockIdx.x & 7) << 7) | (blockIdx.x >> 3);  // 1024 = 8*128
    const int q0  = lb * CHUNK;
    const int wave = tid >> 6, lane = tid & 63;

    // stage reflected in2 patch
    {
        const int y0 = q0 >> 8, x0 = q0 & 255;
        for (int i = tid; i < LSZ * DTC; i += NTHR) {
            int ai = i / DTC, ci = i - ai * DTC;
            dt[i] = in2[refl(y0 + ai) * HWD + refl(x0 + ci)];
        }
    }
    // all 64 row sums from global (ker is L3-resident after S1a).
    // Same products (ker*rcpS1), same stride-64 order, same butterfly as R9.
    for (int o = wave; o < CHUNK; o += 6) {
        const int rb = (q0 + o) * KK;
        float acc = 0.f;
#pragma unroll
        for (int e = lane; e < KK; e += 64)
            acc += ker[rb + e] * rcpS1[(rb + e) & (NPIX - 1)];
        for (int m = 1; m < 64; m <<= 1) acc += __shfl_xor(acc, m);
        if (lane == 0) rowrcp[o] = 1.0f / acc;
    }
    __syncthreads();

    // per-lane chunk-carry state
    const int t  = tid;
    const int j0 = t * NPIX + q0;             // < 2^25
    const int r0 = j0 / KK;
    const int jm = j0 - r0 * KK;
    const int d0 = (jm == 0) ? CHUNK : (KK - jm);
    const int split = d0 < CHUNK ? d0 : CHUNK;     // [1, 64]
    const int la = t / LSZ, lb2 = t - LSZ * la;
    const int dbase = la * DTC + lb2;
    float ad = 0.f, as = 0.f, sd = 0.f, ss = 0.f;

    for (int k = 0; k < CT; ++k) {
        // stage sub-tile k, premultiplied by rcpS1[m] and rowrcp[row]
        const int basek = (q0 + k * QB) * KK;            // %4 == 0
        const float4* k4 = (const float4*)(ker + basek);
        for (int i = tid; i < (QB * KK) / 4; i += NTHR) {
            float4 v = k4[i];
            const int m = basek + i * 4;
            const float4 s = *(const float4*)(rcpS1 + (m & (NPIX - 1)));
            const int idx = i * 4;                        // local elem in sub-tile
            v.x *= s.x * rowrcp[k * QB + (idx    ) / KK];
            v.y *= s.y * rowrcp[k * QB + (idx + 1) / KK];
            v.z *= s.z * rowrcp[k * QB + (idx + 2) / KK];
            v.w *= s.w * rowrcp[k * QB + (idx + 3) / KK];
            *(float4*)(tile + idx) = v;
        }
        __syncthreads();
        // accum: 2 LDS reads + 2 FMA per element
        if (t < KK) {
#pragma unroll
            for (int o = 0; o < QB; ++o) {
                const int off = k * QB + o;
                if (off == split) { sd = ad; ss = as; }   // snapshot at boundary
                float v = tile[o * KK + t];
                float d = dt[dbase + off];
                ad += d * v;
                as += v;
            }
        }
        if (k < CT - 1) __syncthreads();   // tile reused next iteration
    }

    if (t < KK) {
        const int slot = lb & (NSLOT - 1);
        if (split == CHUNK) {
            partial[(size_t)r0 * NSLOT + slot] = float2{ad, as};
        } else {
            partial[(size_t)r0 * NSLOT + slot] = float2{sd, ss};
            partial[(size_t)(r0 + 1) * NSLOT + slot] = float2{ad - sd, as - ss};
        }
    }
}

// ---------------------------------------------------------------------------
// k_out2: sum the valid slot window for row r (no zero-init needed).
// Chunks touching row r: [qs>>6 .. ql>>6] (mod GPART), <= 7 wide;
// slots = chunk & 7, distinct. Whole window lives in ONE 64B line.
// ---------------------------------------------------------------------------
__global__ __launch_bounds__(256) void k_out2(const float2* __restrict__ partial,
                                              float* __restrict__ out) {
    const int r = blockIdx.x * 256 + threadIdx.x;
    const int j0 = r * KK;
    const int qs = j0 & (NPIX - 1);
    const int ql = (j0 + KK - 1) & (NPIX - 1);
    const int first = qs >> 6;
    const int last  = ql >> 6;
    const int cnt = ((last - first) & (GPART - 1)) + 1;
    const float2* p = partial + (size_t)r * NSLOT;
    float dot = 0.f, sum = 0.f;
    for (int i = 0; i < cnt; ++i) {
        float2 v = p[(first + i) & (NSLOT - 1)];
        dot += v.x; sum += v.y;
    }
    out[r] = dot / sum;
}

// ---------------------------------------------------------------------------
// Minimal fallback path (tiny ws): direct strided gathers.
// ---------------------------------------------------------------------------
__global__ __launch_bounds__(256) void k_s1(const float* __restrict__ ker,
                                            float* __restrict__ rcpS1) {
    int p = blockIdx.x * blockDim.x + threadIdx.x;
    const float* kp = ker + p;
    float a = 0.f;
    for (int s = 0; s < KK; ++s) a += kp[(size_t)s * NPIX];
    rcpS1[p] = 1.0f / a;
}

__global__ __launch_bounds__(256) void k_s2_fallback(const float* __restrict__ ker,
                                                     const float* __restrict__ rcpS1,
                                                     float* __restrict__ rcpS2) {
    int lane = threadIdx.x & 63;
    int q = blockIdx.x * 4 + (threadIdx.x >> 6);
    int base = q * KK;
    float acc = 0.f;
    for (int t = lane; t < KK; t += 64)
        acc += ker[base + t] * rcpS1[(base + t) & (NPIX - 1)];
    for (int m = 1; m < 64; m <<= 1) acc += __shfl_xor(acc, m);
    if (lane == 0) rcpS2[q] = 1.0f / acc;
}

__global__ __launch_bounds__(256) void k_out_fallback(const float* __restrict__ ker,
                                                      const float* __restrict__ rcpS1,
                                                      const float* __restrict__ rcpS2,
                                                      const float* __restrict__ in2,
                                                      float* __restrict__ out) {
    int lane = threadIdx.x & 63;
    int r = blockIdx.x * 4 + (threadIdx.x >> 6);
    float vsum = 0.f, vdot = 0.f;
    for (int u = lane; u < KK; u += 64) {
        int jj = r * KK + u;
        int t  = jj >> 16;
        int q  = jj & (NPIX - 1);
        int m  = q * KK + t;
        float v = ker[m] * rcpS1[m & (NPIX - 1)] * rcpS2[q];
        int y = q >> 8, x = q & 255;
        int a = t / LSZ, b = t - a * LSZ;
        float d = in2[refl(y + a) * HWD + refl(x + b)];
        vsum += v;
        vdot += d * v;
    }
    for (int mm = 1; mm < 64; mm <<= 1) {
        vsum += __shfl_xor(vsum, mm);
        vdot += __shfl_xor(vdot, mm);
    }
    if (lane == 0) out[r] = vdot / vsum;
}

extern "C" void kernel_launch(void* const* d_in, const int* in_sizes, int n_in,
                              void* d_out, int out_size, void* d_ws, size_t ws_size,
                              hipStream_t stream) {
    const float* inp = (const float*)d_in[0];   // (1,3,256,256)
    const float* ker = (const float*)d_in[1];   // (19,19,256,256)
    float* out = (float*)d_out;                 // (1,1,256,256)
    const float* in2 = inp + 2 * NPIX;          // channel 2

    float*  rcpS1   = (float*)d_ws;                           // NPIX
    float*  s1part  = rcpS1 + NPIX;                           // NS2*NPIX
    float2* partial = (float2*)(s1part + (size_t)NS2 * NPIX); // NPIX*NSLOT float2

    const size_t needed = ((size_t)NPIX * (1 + NS2) +
                           (size_t)NPIX * NSLOT * 2) * sizeof(float);  // ~8.25 MB

    if (ws_size >= needed) {
        dim3 g1(NPIX / 4 / 256, NS2);   // (64, 16)
        k_s1a<<<g1, 256, 0, stream>>>((const float4*)ker, (float4*)s1part);
        k_s1b<<<NPIX / 4 / 256, 256, 0, stream>>>((const float4*)s1part, (float4*)rcpS1);
        k_part<<<GPART, NTHR, 0, stream>>>(ker, rcpS1, in2, partial);
        k_out2<<<NPIX / 256, 256, 0, stream>>>(partial, out);
    } else {
        float* rcpS2 = rcpS1 + NPIX;   // fallback needs only 512 KB
        k_s1<<<NPIX / 256, 256, 0, stream>>>(ker, rcpS1);
        k_s2_fallback<<<NPIX / 4, 256, 0, stream>>>(ker, rcpS1, rcpS2);
        k_out_fallback<<<NPIX / 4, 256, 0, stream>>>(ker, rcpS1, rcpS2, in2, out);
    }
}

// Round 14
// 49.147 us; speedup vs baseline: 15.7989x; 1.1732x over previous
//
#include <hip/hip_runtime.h>

// Problem constants (hardcoded in the reference)
#define NPIX 65536   // 256*256 = 2^16
#define KK   361     // 19*19
#define LSZ  19
#define HWD  256
#define QB   16      // q-rows per sub-tile
#define CT   4       // sub-tiles per chunk
#define CHUNK 64     // q per block
#define GPART (NPIX / CHUNK)      // 1024 blocks
#define NTHR 384
#define NSLOT 8      // partial slots per row (window <= 7, one 64B line)
#define NS2  16      // s-strips for S1
#define SPS2 23      // s-rows per strip (last: 361 - 15*23 = 16)
#define DTC  82      // in2 LDS tile cols = CHUNK-1 + LSZ

// reflect-pad index (pad=9, size 256, mode="reflect"); arg is (coord + offset)
__device__ __forceinline__ int refl(int v) {
    v -= 9;
    v = v < 0 ? -v : v;
    v = v > 255 ? 510 - v : v;
    return v;
}

// ---------------------------------------------------------------------------
// S1a: partial column sums, contiguous float4 reads (the only cold HBM pass).
// ---------------------------------------------------------------------------
__global__ __launch_bounds__(256) void k_s1a(const float4* __restrict__ ker4,
                                             float4* __restrict__ part4) {
    const int p4 = blockIdx.x * 256 + threadIdx.x;   // [0, 16384)
    const int strip = blockIdx.y;
    const int s0 = strip * SPS2;
    const int n = (strip == NS2 - 1) ? (KK - s0) : SPS2;
    const float4* kp = ker4 + (size_t)s0 * (NPIX / 4) + p4;
    float4 acc = {0.f, 0.f, 0.f, 0.f};
#pragma unroll 8
    for (int s = 0; s < n; ++s) {
        float4 v = kp[(size_t)s * (NPIX / 4)];
        acc.x += v.x; acc.y += v.y; acc.z += v.z; acc.w += v.w;
    }
    part4[(size_t)strip * (NPIX / 4) + p4] = acc;
}

// S1b: rcpS1[p] = 1 / sum_strips
__global__ __launch_bounds__(256) void k_s1b(const float4* __restrict__ part4,
                                             float4* __restrict__ rcp4) {
    const int i = blockIdx.x * 256 + threadIdx.x;    // [0, 16384)
    float4 a = {0.f, 0.f, 0.f, 0.f};
#pragma unroll
    for (int s = 0; s < NS2; ++s) {
        float4 v = part4[(size_t)s * (NPIX / 4) + i];
        a.x += v.x; a.y += v.y; a.z += v.z; a.w += v.w;
    }
    rcp4[i] = float4{1.0f / a.x, 1.0f / a.y, 1.0f / a.z, 1.0f / a.w};
}

// ---------------------------------------------------------------------------
// k_part: R9 structure VERBATIM (best measured: 51.4 us total), plus a
// generation stagger. Blocks q0-swizzled per XCD; per sub-tile k:
//   sync; stage ker*rcpS1 -> tile (float4); sync; rowsum from LDS -> rcpS2s;
//   sync; accum (chunk-carry + snapshot).
// STAGGER: the 4 same-CU generations (g = bid>>8) start simultaneously and
// have identical phase lengths -> barrier convoys keep VMEM (stage) and DS
// (rowsum/accum) phases aligned across co-resident blocks, so the two pipes
// alternate idle. s_sleep(10*g) (~640 cyc steps ~ 1/4 sub-tile period)
// de-phases them so one block's stage overlaps neighbors' accum.
// ---------------------------------------------------------------------------
__global__ __launch_bounds__(NTHR) void k_part(const float* __restrict__ ker,
                                               const float* __restrict__ rcpS1,
                                               const float* __restrict__ in2,
                                               float2* __restrict__ partial) {
    // generation stagger (no effect on results, only phase timing)
    switch (blockIdx.x >> 8) {
        case 1: __builtin_amdgcn_s_sleep(10); break;
        case 2: __builtin_amdgcn_s_sleep(20); break;
        case 3: __builtin_amdgcn_s_sleep(30); break;
        default: break;
    }

    __shared__ float tile[QB * KK];      // 23,104 B
    __shared__ float dt[LSZ * DTC];      // 6,232 B
    __shared__ float rcpS2s[QB];
    const int tid = threadIdx.x;
    const int lb  = ((blockIdx.x & 7) << 7) | (blockIdx.x >> 3);  // 1024 = 8*128
    const int q0  = lb * CHUNK;

    // stage reflected in2 patch (consumed after the k=0 stage barrier)
    {
        const int y0 = q0 >> 8, x0 = q0 & 255;
        for (int i = tid; i < LSZ * DTC; i += NTHR) {
            int ai = i / DTC, ci = i - ai * DTC;
            dt[i] = in2[refl(y0 + ai) * HWD + refl(x0 + ci)];
        }
    }

    // per-lane chunk-carry state
    const int t  = tid;
    const int j0 = t * NPIX + q0;             // < 2^25
    const int r0 = j0 / KK;
    const int jm = j0 - r0 * KK;
    const int d0 = (jm == 0) ? CHUNK : (KK - jm);
    const int split = d0 < CHUNK ? d0 : CHUNK;     // [1, 64]
    const int la = t / LSZ, lb2 = t - LSZ * la;
    const int dbase = la * DTC + lb2;
    float ad = 0.f, as = 0.f, sd = 0.f, ss = 0.f;
    const int wave = tid >> 6, lane = tid & 63;

    for (int k = 0; k < CT; ++k) {
        __syncthreads();   // previous sub-tile fully consumed (and dt, k=0)
        // stage ker sub-tile k (coalesced float4), scaled by rcpS1
        const int basek = (q0 + k * QB) * KK;            // %4 == 0
        const float4* k4 = (const float4*)(ker + basek);
        for (int i = tid; i < (QB * KK) / 4; i += NTHR) {
            float4 v = k4[i];
            int m = basek + i * 4;
            const float4 s = *(const float4*)(rcpS1 + (m & (NPIX - 1)));
            v.x *= s.x; v.y *= s.y; v.z *= s.z; v.w *= s.w;
            *(float4*)(tile + i * 4) = v;
        }
        __syncthreads();
        // per-q row sums -> rcpS2s
        for (int qq = wave; qq < QB; qq += 6) {
            float acc = 0.f;
            for (int e = lane; e < KK; e += 64) acc += tile[qq * KK + e];
            for (int m = 1; m < 64; m <<= 1) acc += __shfl_xor(acc, m);
            if (lane == 0) rcpS2s[qq] = 1.0f / acc;
        }
        __syncthreads();
        if (t < KK) {
#pragma unroll
            for (int o = 0; o < QB; ++o) {
                const int off = k * QB + o;
                if (off == split) { sd = ad; ss = as; }  // snapshot at boundary
                float v = tile[o * KK + t] * rcpS2s[o];
                float d = dt[dbase + off];
                ad += d * v;
                as += v;
            }
        }
    }

    if (t < KK) {
        const int slot = lb & (NSLOT - 1);
        if (split == CHUNK) {
            partial[(size_t)r0 * NSLOT + slot] = float2{ad, as};
        } else {
            partial[(size_t)r0 * NSLOT + slot] = float2{sd, ss};
            partial[(size_t)(r0 + 1) * NSLOT + slot] = float2{ad - sd, as - ss};
        }
    }
}

// ---------------------------------------------------------------------------
// k_out2: sum the valid slot window for row r (no zero-init needed).
// Chunks touching row r: [qs>>6 .. ql>>6] (mod GPART), <= 7 wide;
// slots = chunk & 7, distinct. Whole window lives in ONE 64B line.
// ---------------------------------------------------------------------------
__global__ __launch_bounds__(256) void k_out2(const float2* __restrict__ partial,
                                              float* __restrict__ out) {
    const int r = blockIdx.x * 256 + threadIdx.x;
    const int j0 = r * KK;
    const int qs = j0 & (NPIX - 1);
    const int ql = (j0 + KK - 1) & (NPIX - 1);
    const int first = qs >> 6;
    const int last  = ql >> 6;
    const int cnt = ((last - first) & (GPART - 1)) + 1;
    const float2* p = partial + (size_t)r * NSLOT;
    float dot = 0.f, sum = 0.f;
    for (int i = 0; i < cnt; ++i) {
        float2 v = p[(first + i) & (NSLOT - 1)];
        dot += v.x; sum += v.y;
    }
    out[r] = dot / sum;
}

// ---------------------------------------------------------------------------
// Minimal fallback path (tiny ws): direct strided gathers.
// ---------------------------------------------------------------------------
__global__ __launch_bounds__(256) void k_s1(const float* __restrict__ ker,
                                            float* __restrict__ rcpS1) {
    int p = blockIdx.x * blockDim.x + threadIdx.x;
    const float* kp = ker + p;
    float a = 0.f;
    for (int s = 0; s < KK; ++s) a += kp[(size_t)s * NPIX];
    rcpS1[p] = 1.0f / a;
}

__global__ __launch_bounds__(256) void k_s2_fallback(const float* __restrict__ ker,
                                                     const float* __restrict__ rcpS1,
                                                     float* __restrict__ rcpS2) {
    int lane = threadIdx.x & 63;
    int q = blockIdx.x * 4 + (threadIdx.x >> 6);
    int base = q * KK;
    float acc = 0.f;
    for (int t = lane; t < KK; t += 64)
        acc += ker[base + t] * rcpS1[(base + t) & (NPIX - 1)];
    for (int m = 1; m < 64; m <<= 1) acc += __shfl_xor(acc, m);
    if (lane == 0) rcpS2[q] = 1.0f / acc;
}

__global__ __launch_bounds__(256) void k_out_fallback(const float* __restrict__ ker,
                                                      const float* __restrict__ rcpS1,
                                                      const float* __restrict__ rcpS2,
                                                      const float* __restrict__ in2,
                                                      float* __restrict__ out) {
    int lane = threadIdx.x & 63;
    int r = blockIdx.x * 4 + (threadIdx.x >> 6);
    float vsum = 0.f, vdot = 0.f;
    for (int u = lane; u < KK; u += 64) {
        int jj = r * KK + u;
        int t  = jj >> 16;
        int q  = jj & (NPIX - 1);
        int m  = q * KK + t;
        float v = ker[m] * rcpS1[m & (NPIX - 1)] * rcpS2[q];
        int y = q >> 8, x = q & 255;
        int a = t / LSZ, b = t - a * LSZ;
        float d = in2[refl(y + a) * HWD + refl(x + b)];
        vsum += v;
        vdot += d * v;
    }
    for (int mm = 1; mm < 64; mm <<= 1) {
        vsum += __shfl_xor(vsum, mm);
        vdot += __shfl_xor(vdot, mm);
    }
    if (lane == 0) out[r] = vdot / vsum;
}

extern "C" void kernel_launch(void* const* d_in, const int* in_sizes, int n_in,
                              void* d_out, int out_size, void* d_ws, size_t ws_size,
                              hipStream_t stream) {
    const float* inp = (const float*)d_in[0];   // (1,3,256,256)
    const float* ker = (const float*)d_in[1];   // (19,19,256,256)
    float* out = (float*)d_out;                 // (1,1,256,256)
    const float* in2 = inp + 2 * NPIX;          // channel 2

    float*  rcpS1   = (float*)d_ws;                           // NPIX
    float*  s1part  = rcpS1 + NPIX;                           // NS2*NPIX
    float2* partial = (float2*)(s1part + (size_t)NS2 * NPIX); // NPIX*NSLOT float2

    const size_t needed = ((size_t)NPIX * (1 + NS2) +
                           (size_t)NPIX * NSLOT * 2) * sizeof(float);  // ~8.25 MB

    if (ws_size >= needed) {
        dim3 g1(NPIX / 4 / 256, NS2);   // (64, 16)
        k_s1a<<<g1, 256, 0, stream>>>((const float4*)ker, (float4*)s1part);
        k_s1b<<<NPIX / 4 / 256, 256, 0, stream>>>((const float4*)s1part, (float4*)rcpS1);
        k_part<<<GPART, NTHR, 0, stream>>>(ker, rcpS1, in2, partial);
        k_out2<<<NPIX / 256, 256, 0, stream>>>(partial, out);
    } else {
        float* rcpS2 = rcpS1 + NPIX;   // fallback needs only 512 KB
        k_s1<<<NPIX / 256, 256, 0, stream>>>(ker, rcpS1);
        k_s2_fallback<<<NPIX / 4, 256, 0, stream>>>(ker, rcpS1, rcpS2);
        k_out_fallback<<<NPIX / 4, 256, 0, stream>>>(ker, rcpS1, rcpS2, in2, out);
    }
}